// Round 2
// baseline (766.692 us; speedup 1.0000x reference)
//
#include <hip/hip_runtime.h>
#include <hip/hip_bf16.h>
#include <math.h>
#include <stdint.h>

// Problem constants (B=2, T=1024 -> N=2048 tokens)
#define N_TOK   2048
#define C_DIM   2048
#define E_NUM   8
#define F_MOE   1408
#define F_SH    5632
#define SLOTS   4096            // N_TOK * TOPK
#define PADROWS 4224            // SLOTS + 128 slack for tile-tail reads

typedef __bf16 bf16;
typedef __bf16 bf16x8 __attribute__((ext_vector_type(8)));
typedef float  f32x4  __attribute__((ext_vector_type(4)));

__device__ __forceinline__ f32x4 mfma16(bf16x8 a, bf16x8 b, f32x4 c) {
    return __builtin_amdgcn_mfma_f32_16x16x32_bf16(a, b, c, 0, 0, 0);
}

// async global->LDS, 16B per lane. LDS dest is wave-uniform base + lane*16.
__device__ __forceinline__ void gload16(const void* g, void* l) {
    __builtin_amdgcn_global_load_lds(
        (const __attribute__((address_space(1))) void*)g,
        (__attribute__((address_space(3))) void*)l,
        16, 0, 0);
}

// ---------------------------------------------------------------------------
// Router: logits = x @ gate_w^T (8), shared gate logit (1); softmax fp32,
// top-2 (lowest index on ties); sigmoid gate. One block per token.
// ---------------------------------------------------------------------------
__global__ void router_kernel(const float* __restrict__ x,
                              const float* __restrict__ gate_w,
                              const float* __restrict__ sgate_w,
                              int* __restrict__ slotexp,
                              float* __restrict__ slotp,
                              float* __restrict__ sig)
{
    const int n   = blockIdx.x;
    const int tid = threadIdx.x;            // 256 threads
    const float* xr = x + (size_t)n * C_DIM;
    const int c0 = tid * 8;

    float xv[8];
#pragma unroll
    for (int j = 0; j < 8; ++j) xv[j] = xr[c0 + j];

    float dots[9];
#pragma unroll
    for (int e = 0; e < 9; ++e) {
        const float* wr = (e < 8) ? (gate_w + (size_t)e * C_DIM) : sgate_w;
        float p = 0.f;
#pragma unroll
        for (int j = 0; j < 8; ++j) p += xv[j] * wr[c0 + j];
#pragma unroll
        for (int off = 32; off > 0; off >>= 1) p += __shfl_down(p, off);
        dots[e] = p;
    }

    __shared__ float red[4][9];
    const int wid = tid >> 6, lane = tid & 63;
    if (lane == 0) {
#pragma unroll
        for (int e = 0; e < 9; ++e) red[wid][e] = dots[e];
    }
    __syncthreads();
    if (tid == 0) {
        float l[9];
#pragma unroll
        for (int e = 0; e < 9; ++e)
            l[e] = red[0][e] + red[1][e] + red[2][e] + red[3][e];
        float mx = l[0];
#pragma unroll
        for (int e = 1; e < 8; ++e) mx = fmaxf(mx, l[e]);
        float p[8], s = 0.f;
#pragma unroll
        for (int e = 0; e < 8; ++e) { p[e] = expf(l[e] - mx); s += p[e]; }
        const float inv = 1.f / s;
#pragma unroll
        for (int e = 0; e < 8; ++e) p[e] *= inv;
        int i1 = 0;
#pragma unroll
        for (int e = 1; e < 8; ++e) if (p[e] > p[i1]) i1 = e;
        int i2 = (i1 == 0) ? 1 : 0;
#pragma unroll
        for (int e = 0; e < 8; ++e) if (e != i1 && p[e] > p[i2]) i2 = e;
        slotexp[2 * n]     = i1;  slotp[2 * n]     = p[i1];
        slotexp[2 * n + 1] = i2;  slotp[2 * n + 1] = p[i2];
        sig[n] = 1.f / (1.f + expf(-l[8]));
    }
}

// ---------------------------------------------------------------------------
// Stable scatter: one block, 8 waves, wave e owns expert e.
// ---------------------------------------------------------------------------
__global__ void scatter_kernel(const int* __restrict__ slotexp,
                               const float* __restrict__ slotp,
                               int* __restrict__ counts, int* __restrict__ bases,
                               int* __restrict__ pos_of, int* __restrict__ row_token,
                               float* __restrict__ rowscale)
{
    const int tid = threadIdx.x;            // 512 threads = 8 waves
    const int w = tid >> 6, lane = tid & 63;
    __shared__ int cnt[E_NUM], base[E_NUM];

    int run = 0;
    for (int s0 = 0; s0 < SLOTS; s0 += 64) {
        int e = slotexp[s0 + lane];
        unsigned long long m = __ballot(e == w);
        run += __popcll(m);
    }
    if (lane == 0) cnt[w] = run;
    __syncthreads();
    if (tid == 0) {
        int b = 0;
        for (int e = 0; e < E_NUM; ++e) { base[e] = b; b += cnt[e]; }
    }
    __syncthreads();
    run = 0;
    for (int s0 = 0; s0 < SLOTS; s0 += 64) {
        const int s = s0 + lane;
        const int e = slotexp[s];
        unsigned long long m = __ballot(e == w);
        if (e == w) {
            const unsigned long long lt = (lane == 0) ? 0ull : (~0ull >> (64 - lane));
            const int pos = base[w] + run + __popcll(m & lt);
            pos_of[s]      = pos;
            row_token[pos] = s >> 1;
            rowscale[pos]  = slotp[s];
        }
        run += __popcll(m);
    }
    if (lane == 0) { counts[w] = cnt[w]; bases[w] = base[w]; }
}

// ---------------------------------------------------------------------------
// f32 -> bf16 elementwise, 8 elems/thread (n must be multiple of 2048)
// ---------------------------------------------------------------------------
__global__ void cvt_kernel(const float* __restrict__ in, bf16* __restrict__ out)
{
    const size_t i = ((size_t)blockIdx.x * 256 + threadIdx.x) * 8;
    f32x4 a = *(const f32x4*)(in + i);
    f32x4 b = *(const f32x4*)(in + i + 4);
    bf16x8 o;
#pragma unroll
    for (int j = 0; j < 4; ++j) { o[j] = (bf16)a[j]; o[4 + j] = (bf16)b[j]; }
    *(bf16x8*)(out + i) = o;
}

// ---------------------------------------------------------------------------
// Gather token rows into per-expert-contiguous Xg. One block per position.
// ---------------------------------------------------------------------------
__global__ void gather_kernel(const bf16* __restrict__ Xs,
                              const int* __restrict__ row_token,
                              bf16* __restrict__ Xg)
{
    const int pos = blockIdx.x;
    const int t   = row_token[pos];
    const bf16x8* s = (const bf16x8*)(Xs + (size_t)t * C_DIM);
    bf16x8*       d = (bf16x8*)(Xg + (size_t)pos * C_DIM);
    d[threadIdx.x] = s[threadIdx.x];        // 256 * 8 = 2048 elems
}

// ---------------------------------------------------------------------------
// NT GEMM, all-bf16: out[m,n] = sum_k A[m,k] * B[n,k].
// m97 structure: 128x128 tile, BK=32, global_load_lds(16B) direct to linear
// LDS, 2-barrier K-loop, 4 waves each computing 64x64 via 4x4 16x16x32 MFMAs.
// DUAL:   two B matrices, epilogue H = silu(A@B1^T) * (A@B2^T) -> bf16
// !DUAL:  epilogue out = rowscale[m] * (A@B^T) -> f32
// GROUPED: blockIdx.z = expert; rows [bases[e], bases[e]+counts[e]).
// ---------------------------------------------------------------------------
template<bool DUAL, bool GROUPED>
__global__ __launch_bounds__(256)
void gemm_nt(const bf16* __restrict__ A, int lda,
             const bf16* __restrict__ B1g, const bf16* __restrict__ B2g,
             size_t strideB,
             bf16* __restrict__ OUTh, float* __restrict__ OUTf, int ldo,
             const float* __restrict__ rowscale,
             const int* __restrict__ bases, const int* __restrict__ counts,
             int M, int N, int K)
{
    const int e    = GROUPED ? blockIdx.z : 0;
    const int base = GROUPED ? bases[e]  : 0;
    const int cnt  = GROUPED ? counts[e] : M;
    const int mt = blockIdx.y, nt = blockIdx.x;
    if (GROUPED && mt * 128 >= cnt) return;

    const bf16* B1 = B1g + (size_t)e * strideB;
    const bf16* B2 = DUAL ? (B2g + (size_t)e * strideB) : (const bf16*)nullptr;

    __shared__ bf16 sA [128][32];
    __shared__ bf16 sB1[128][32];
    __shared__ bf16 sB2[DUAL ? 128 : 1][32];

    const int tid  = threadIdx.x;
    const int wid  = tid >> 6, lane = tid & 63;

    // staging geometry: wave w covers rows [w*32, w*32+32) of the 128x32 tile
    // issue i in {0,1}: lane l writes LDS bytes w*2048 + i*1024 + l*16
    //                   == row w*32 + i*16 + (l>>2), bf16 col (l&3)*8
    const int sr = wid * 32 + (lane >> 2);
    const int sc = (lane & 3) * 8;
    const bf16* Ag  = A  + (size_t)(base + mt * 128 + sr) * lda + sc;
    const bf16* B1p = B1 + (size_t)(nt * 128 + sr) * K + sc;
    const bf16* B2p = DUAL ? (B2 + (size_t)(nt * 128 + sr) * K + sc) : (const bf16*)nullptr;

    bf16* lA  = &sA [0][0] + wid * 1024;     // wave-uniform LDS bases
    bf16* lB1 = &sB1[0][0] + wid * 1024;
    bf16* lB2 = DUAL ? (&sB2[0][0] + wid * 1024) : (bf16*)nullptr;

    const int wr = (wid >> 1) * 64, wc = (wid & 1) * 64;
    const int fr = lane & 15, fq = lane >> 4;

    f32x4 acc1[4][4] = {};
    f32x4 acc2[DUAL ? 4 : 1][4] = {};

    const int KT = K / 32;
    for (int kt = 0; kt < KT; ++kt) {
        __syncthreads();                     // prev compute done -> LDS free
        const size_t ko = (size_t)kt * 32;
        gload16(Ag + ko,                lA);
        gload16(Ag + 16 * (size_t)lda + ko, lA + 512);
        gload16(B1p + ko,               lB1);
        gload16(B1p + 16 * (size_t)K + ko,  lB1 + 512);
        if constexpr (DUAL) {
            gload16(B2p + ko,               lB2);
            gload16(B2p + 16 * (size_t)K + ko,  lB2 + 512);
        }
        __syncthreads();                     // vmcnt(0) drained by barrier

        bf16x8 af[4], bfr[4];
#pragma unroll
        for (int m = 0; m < 4; ++m) af[m]  = *(const bf16x8*)&sA [wr + m * 16 + fr][fq * 8];
#pragma unroll
        for (int n = 0; n < 4; ++n) bfr[n] = *(const bf16x8*)&sB1[wc + n * 16 + fr][fq * 8];
#pragma unroll
        for (int m = 0; m < 4; ++m)
#pragma unroll
            for (int n = 0; n < 4; ++n)
                acc1[m][n] = mfma16(af[m], bfr[n], acc1[m][n]);
        if constexpr (DUAL) {
            bf16x8 bf2[4];
#pragma unroll
            for (int n = 0; n < 4; ++n) bf2[n] = *(const bf16x8*)&sB2[wc + n * 16 + fr][fq * 8];
#pragma unroll
            for (int m = 0; m < 4; ++m)
#pragma unroll
                for (int n = 0; n < 4; ++n)
                    acc2[m][n] = mfma16(af[m], bf2[n], acc2[m][n]);
        }
    }

    // Epilogue. C/D layout: col = lane&15, row = (lane>>4)*4 + j  (m89)
#pragma unroll
    for (int m = 0; m < 4; ++m) {
#pragma unroll
        for (int j = 0; j < 4; ++j) {
            const int r = mt * 128 + wr + m * 16 + fq * 4 + j;
            if (GROUPED && r >= cnt) continue;
            const size_t orow = (size_t)(base + r) * (size_t)ldo;
            if constexpr (DUAL) {
#pragma unroll
                for (int n = 0; n < 4; ++n) {
                    const int col = nt * 128 + wc + n * 16 + fr;
                    const float h1 = acc1[m][n][j];
                    const float h2 = acc2[m][n][j];
                    OUTh[orow + col] = (bf16)(h1 / (1.f + expf(-h1)) * h2);
                }
            } else {
                const float sc2 = rowscale[base + r];
#pragma unroll
                for (int n = 0; n < 4; ++n) {
                    const int col = nt * 128 + wc + n * 16 + fr;
                    OUTf[orow + col] = sc2 * acc1[m][n][j];
                }
            }
        }
    }
}

// ---------------------------------------------------------------------------
// y[n] += Eout[pos0(n)] + Eout[pos1(n)]   (y already holds shared output)
// ---------------------------------------------------------------------------
__global__ void combine_kernel(const float* __restrict__ Eout,
                               const int* __restrict__ pos_of,
                               float* __restrict__ y)
{
    const int n  = blockIdx.x;
    const int p0 = pos_of[2 * n], p1 = pos_of[2 * n + 1];
    const f32x4* a = (const f32x4*)(Eout + (size_t)p0 * C_DIM);
    const f32x4* b = (const f32x4*)(Eout + (size_t)p1 * C_DIM);
    f32x4*       o = (f32x4*)(y + (size_t)n * C_DIM);
#pragma unroll
    for (int i = threadIdx.x; i < C_DIM / 4; i += 256)
        o[i] = o[i] + a[i] + b[i];
}

// ---------------------------------------------------------------------------
extern "C" void kernel_launch(void* const* d_in, const int* in_sizes, int n_in,
                              void* d_out, int out_size, void* d_ws, size_t ws_size,
                              hipStream_t stream)
{
    const float* x     = (const float*)d_in[0];
    const float* gatew = (const float*)d_in[1];
    const float* efc1  = (const float*)d_in[2];
    const float* efc2  = (const float*)d_in[3];
    const float* eproj = (const float*)d_in[4];
    const float* sfc1  = (const float*)d_in[5];
    const float* sfc2  = (const float*)d_in[6];
    const float* sproj = (const float*)d_in[7];
    const float* sgate = (const float*)d_in[8];
    float* y = (float*)d_out;

    // workspace carve-up (all 256B-aligned)
    char* w = (char*)d_ws;
    size_t off = 0;
    auto take = [&](size_t bytes) {
        char* p = w + off;
        off = (off + bytes + 255) & ~(size_t)255;
        return p;
    };
    int*   counts    = (int*)  take(E_NUM * 4);
    int*   bases     = (int*)  take(E_NUM * 4);
    int*   slotexp   = (int*)  take(SLOTS * 4);
    float* slotp     = (float*)take(SLOTS * 4);
    int*   pos_of    = (int*)  take(SLOTS * 4);
    int*   row_token = (int*)  take(PADROWS * 4);
    float* rowscale  = (float*)take(PADROWS * 4);
    float* sig       = (float*)take(N_TOK * 4);
    bf16*  Xs        = (bf16*) take((size_t)N_TOK   * C_DIM * 2);
    bf16*  Xg        = (bf16*) take((size_t)PADROWS * C_DIM * 2);
    bf16*  Hs        = (bf16*) take((size_t)N_TOK   * F_SH  * 2);
    bf16*  Hm        = (bf16*) take((size_t)PADROWS * F_MOE * 2);
    float* Eout      = (float*)take((size_t)PADROWS * C_DIM * 4);
    bf16*  Wefc1     = (bf16*) take((size_t)E_NUM * F_MOE * C_DIM * 2);
    bf16*  Wefc2     = (bf16*) take((size_t)E_NUM * F_MOE * C_DIM * 2);
    bf16*  Weproj    = (bf16*) take((size_t)E_NUM * C_DIM * F_MOE * 2);
    bf16*  Wsfc1     = (bf16*) take((size_t)F_SH * C_DIM * 2);
    bf16*  Wsfc2     = (bf16*) take((size_t)F_SH * C_DIM * 2);
    bf16*  Wsproj    = (bf16*) take((size_t)C_DIM * F_SH * 2);
    (void)ws_size; (void)in_sizes; (void)n_in; (void)out_size;

    // weight + activation f32->bf16 conversion (each size multiple of 2048)
    cvt_kernel<<<(N_TOK * C_DIM) / 2048, 256, 0, stream>>>(x, Xs);
    cvt_kernel<<<(E_NUM * F_MOE * C_DIM) / 2048, 256, 0, stream>>>(efc1, Wefc1);
    cvt_kernel<<<(E_NUM * F_MOE * C_DIM) / 2048, 256, 0, stream>>>(efc2, Wefc2);
    cvt_kernel<<<(E_NUM * C_DIM * F_MOE) / 2048, 256, 0, stream>>>(eproj, Weproj);
    cvt_kernel<<<(F_SH * C_DIM) / 2048, 256, 0, stream>>>(sfc1, Wsfc1);
    cvt_kernel<<<(F_SH * C_DIM) / 2048, 256, 0, stream>>>(sfc2, Wsfc2);
    cvt_kernel<<<(C_DIM * F_SH) / 2048, 256, 0, stream>>>(sproj, Wsproj);

    router_kernel<<<N_TOK, 256, 0, stream>>>(x, gatew, sgate, slotexp, slotp, sig);
    scatter_kernel<<<1, 512, 0, stream>>>(slotexp, slotp, counts, bases,
                                          pos_of, row_token, rowscale);
    gather_kernel<<<SLOTS, 256, 0, stream>>>(Xs, row_token, Xg);

    // shared expert: Hs = silu(Xs@fc1^T)*(Xs@fc2^T)   [2048 x 5632]
    gemm_nt<true, false><<<dim3(F_SH / 128, N_TOK / 128, 1), 256, 0, stream>>>(
        Xs, C_DIM, Wsfc1, Wsfc2, 0, Hs, nullptr, F_SH,
        nullptr, nullptr, nullptr, N_TOK, F_SH, C_DIM);

    // MoE experts (grouped): Hm = silu(Xg@fc1_e^T)*(Xg@fc2_e^T)  [cnt_e x 1408]
    gemm_nt<true, true><<<dim3(F_MOE / 128, N_TOK / 128, E_NUM), 256, 0, stream>>>(
        Xg, C_DIM, Wefc1, Wefc2, (size_t)F_MOE * C_DIM, Hm, nullptr, F_MOE,
        nullptr, bases, counts, 0, F_MOE, C_DIM);

    // shared proj -> y directly: y = sig[n] * (Hs @ sproj^T)   [2048 x 2048]
    gemm_nt<false, false><<<dim3(C_DIM / 128, N_TOK / 128, 1), 256, 0, stream>>>(
        Hs, F_SH, Wsproj, nullptr, 0, nullptr, y, C_DIM,
        sig, nullptr, nullptr, N_TOK, C_DIM, F_SH);

    // MoE proj (grouped): Eout = p[slot] * (Hm @ proj_e^T)  [cnt_e x 2048]
    gemm_nt<false, true><<<dim3(C_DIM / 128, N_TOK / 128, E_NUM), 256, 0, stream>>>(
        Hm, F_MOE, Weproj, nullptr, (size_t)C_DIM * F_MOE, nullptr, Eout, C_DIM,
        rowscale, bases, counts, 0, C_DIM, F_MOE);

    combine_kernel<<<N_TOK, 256, 0, stream>>>(Eout, pos_of, y);
}

// Round 4
// 522.700 us; speedup vs baseline: 1.4668x; 1.4668x over previous
//
#include <hip/hip_runtime.h>
#include <hip/hip_bf16.h>
#include <math.h>
#include <stdint.h>

// Problem constants (B=2, T=1024 -> N=2048 tokens)
#define N_TOK   2048
#define C_DIM   2048
#define E_NUM   8
#define F_MOE   1408
#define F_SH    5632
#define SLOTS   4096            // N_TOK * TOPK
#define PADROWS 4608            // SLOTS + 512 slack for 256-row tile tails

typedef __bf16 bf16;
typedef __bf16 bf16x8 __attribute__((ext_vector_type(8)));
typedef float  f32x4  __attribute__((ext_vector_type(4)));

__device__ __forceinline__ f32x4 mfma16(bf16x8 a, bf16x8 b, f32x4 c) {
    return __builtin_amdgcn_mfma_f32_16x16x32_bf16(a, b, c, 0, 0, 0);
}
__device__ __forceinline__ void gload16(const void* g, void* l) {
    __builtin_amdgcn_global_load_lds(
        (const __attribute__((address_space(1))) void*)g,
        (__attribute__((address_space(3))) void*)l, 16, 0, 0);
}
#define RAWBAR() asm volatile("s_barrier" ::: "memory")
#define VMCNT8() asm volatile("s_waitcnt vmcnt(8)" ::: "memory")
#define VMCNT0() asm volatile("s_waitcnt vmcnt(0)" ::: "memory")

// ---------------------------------------------------------------------------
// Router (unchanged, verified)
// ---------------------------------------------------------------------------
__global__ void router_kernel(const float* __restrict__ x,
                              const float* __restrict__ gate_w,
                              const float* __restrict__ sgate_w,
                              int* __restrict__ slotexp,
                              float* __restrict__ slotp,
                              float* __restrict__ sig)
{
    const int n   = blockIdx.x;
    const int tid = threadIdx.x;            // 256 threads
    const float* xr = x + (size_t)n * C_DIM;
    const int c0 = tid * 8;

    float xv[8];
#pragma unroll
    for (int j = 0; j < 8; ++j) xv[j] = xr[c0 + j];

    float dots[9];
#pragma unroll
    for (int e = 0; e < 9; ++e) {
        const float* wr = (e < 8) ? (gate_w + (size_t)e * C_DIM) : sgate_w;
        float p = 0.f;
#pragma unroll
        for (int j = 0; j < 8; ++j) p += xv[j] * wr[c0 + j];
#pragma unroll
        for (int off = 32; off > 0; off >>= 1) p += __shfl_down(p, off);
        dots[e] = p;
    }

    __shared__ float red[4][9];
    const int wid = tid >> 6, lane = tid & 63;
    if (lane == 0) {
#pragma unroll
        for (int e = 0; e < 9; ++e) red[wid][e] = dots[e];
    }
    __syncthreads();
    if (tid == 0) {
        float l[9];
#pragma unroll
        for (int e = 0; e < 9; ++e)
            l[e] = red[0][e] + red[1][e] + red[2][e] + red[3][e];
        float mx = l[0];
#pragma unroll
        for (int e = 1; e < 8; ++e) mx = fmaxf(mx, l[e]);
        float p[8], s = 0.f;
#pragma unroll
        for (int e = 0; e < 8; ++e) { p[e] = expf(l[e] - mx); s += p[e]; }
        const float inv = 1.f / s;
#pragma unroll
        for (int e = 0; e < 8; ++e) p[e] *= inv;
        int i1 = 0;
#pragma unroll
        for (int e = 1; e < 8; ++e) if (p[e] > p[i1]) i1 = e;
        int i2 = (i1 == 0) ? 1 : 0;
#pragma unroll
        for (int e = 0; e < 8; ++e) if (e != i1 && p[e] > p[i2]) i2 = e;
        slotexp[2 * n]     = i1;  slotp[2 * n]     = p[i1];
        slotexp[2 * n + 1] = i2;  slotp[2 * n + 1] = p[i2];
        sig[n] = 1.f / (1.f + expf(-l[8]));
    }
}

// ---------------------------------------------------------------------------
// Stable scatter (unchanged, verified)
// ---------------------------------------------------------------------------
__global__ void scatter_kernel(const int* __restrict__ slotexp,
                               int* __restrict__ counts, int* __restrict__ bases,
                               int* __restrict__ pos_of, int* __restrict__ row_token)
{
    const int tid = threadIdx.x;            // 512 threads = 8 waves
    const int w = tid >> 6, lane = tid & 63;
    __shared__ int cnt[E_NUM], base[E_NUM];

    int run = 0;
    for (int s0 = 0; s0 < SLOTS; s0 += 64) {
        int e = slotexp[s0 + lane];
        unsigned long long m = __ballot(e == w);
        run += __popcll(m);
    }
    if (lane == 0) cnt[w] = run;
    __syncthreads();
    if (tid == 0) {
        int b = 0;
        for (int e = 0; e < E_NUM; ++e) { base[e] = b; b += cnt[e]; }
    }
    __syncthreads();
    run = 0;
    for (int s0 = 0; s0 < SLOTS; s0 += 64) {
        const int s = s0 + lane;
        const int e = slotexp[s];
        unsigned long long m = __ballot(e == w);
        if (e == w) {
            const unsigned long long lt = (lane == 0) ? 0ull : (~0ull >> (64 - lane));
            const int pos = base[w] + run + __popcll(m & lt);
            pos_of[s]      = pos;
            row_token[pos] = s >> 1;
        }
        run += __popcll(m);
    }
    if (lane == 0) { counts[w] = cnt[w]; bases[w] = base[w]; }
}

// ---------------------------------------------------------------------------
// f32 -> bf16 elementwise, 8 elems/thread (size multiple of 2048)
// ---------------------------------------------------------------------------
__global__ void cvt_kernel(const float* __restrict__ in, bf16* __restrict__ out)
{
    const size_t i = ((size_t)blockIdx.x * 256 + threadIdx.x) * 8;
    f32x4 a = *(const f32x4*)(in + i);
    f32x4 b = *(const f32x4*)(in + i + 4);
    bf16x8 o;
#pragma unroll
    for (int j = 0; j < 4; ++j) { o[j] = (bf16)a[j]; o[4 + j] = (bf16)b[j]; }
    *(bf16x8*)(out + i) = o;
}

// ---------------------------------------------------------------------------
// Gather token rows into per-expert-contiguous Xg.
// ---------------------------------------------------------------------------
__global__ void gather_kernel(const bf16* __restrict__ Xs,
                              const int* __restrict__ row_token,
                              bf16* __restrict__ Xg)
{
    const int pos = blockIdx.x;
    const int t   = row_token[pos];
    const bf16x8* s = (const bf16x8*)(Xs + (size_t)t * C_DIM);
    bf16x8*       d = (bf16x8*)(Xg + (size_t)pos * C_DIM);
    d[threadIdx.x] = s[threadIdx.x];
}

// ---------------------------------------------------------------------------
// 8-phase-family NT GEMM (T2+T3+T4+T5).  out[m,n] = sum_k A[m,k]*B[n,k].
// BM=256 rows, BK=64, 8 waves (2Mx4N), double-buffered 128KiB LDS,
// global_load_lds(16B) with inverse-swizzled source, XOR-swizzled ds_read
// (chunk ^= row&7 -> 2-way max, free), counted vmcnt(8) (never drains in
// steady state), 4 phases/K-tile each {ds_read subtile; s_barrier; setprio(1)
// 16xMFMA setprio(0)}.
// DUAL:  B-tile rows 0-127 = B1 panel, 128-255 = B2 panel (BN=128/matrix);
//        epilogue Hm = silu(h1)*h2 -> bf16.
// !DUAL: BN=256, raw f32 output (scales applied in combine).
// GROUPED: blockIdx.z = expert; epilogue masks rows >= base+cnt (expert e's
//          tile tail overlaps expert e+1's rows -- the round-3 race).
// KSPLIT>1: blockIdx.z = K-part (partials into OUTf + kp*strideOut).
// ---------------------------------------------------------------------------
template<bool DUAL, bool GROUPED, int KSPLIT>
__global__ __launch_bounds__(512, 1)
void gemm8(const bf16* __restrict__ A, int lda,
           const bf16* __restrict__ B1g, const bf16* __restrict__ B2g,
           size_t strideB,
           bf16* __restrict__ OUTh, float* __restrict__ OUTf, int ldo,
           size_t strideOut,
           const int* __restrict__ bases, const int* __restrict__ counts,
           int K)
{
    __shared__ char lds[131072];

    const int e    = GROUPED ? blockIdx.z : 0;
    const int base = GROUPED ? bases[e] : 0;
    const int cnt  = GROUPED ? counts[e] : 0x7fffffff;
    if (GROUPED && (int)blockIdx.y * 256 >= cnt) return;
    const int kp  = (KSPLIT > 1) ? (int)blockIdx.z : 0;
    const int KT  = (K / 64) / KSPLIT;

    const int m0 = base + blockIdx.y * 256;
    const int nt = blockIdx.x;

    const int tid = threadIdx.x;
    const int w = tid >> 6, lane = tid & 63;
    const int l8 = lane >> 3, c8 = lane & 7;
    const int schunk = (c8 ^ l8) << 4;       // inverse-swizzled source chunk

    // --- staging addresses -------------------------------------------------
    const char* Abase = (const char*)A + (size_t)kp * KT * 128;
    uint32_t aOff[4];
#pragma unroll
    for (int i = 0; i < 4; ++i) {
        const int r = m0 + w * 32 + i * 8 + l8;
        aOff[i] = (uint32_t)r * (uint32_t)(lda * 2) + (uint32_t)schunk;
    }

    const bf16* B1 = B1g + (GROUPED ? (size_t)e * strideB : 0);
    const char* Bbase;
    uint32_t bOff[4];
    if constexpr (DUAL) {
        const bf16* B2 = B2g + (GROUPED ? (size_t)e * strideB : 0);
        Bbase = (const char*)(w < 4 ? B1 : B2);
        const int n0 = nt * 128 + (w & 3) * 32;
#pragma unroll
        for (int i = 0; i < 4; ++i) {
            const int r = n0 + i * 8 + l8;
            bOff[i] = (uint32_t)r * (uint32_t)(K * 2) + (uint32_t)schunk;
        }
    } else {
        Bbase = (const char*)B1;
        const int n0 = nt * 256 + w * 32;
#pragma unroll
        for (int i = 0; i < 4; ++i) {
            const int r = n0 + i * 8 + l8;
            bOff[i] = (uint32_t)r * (uint32_t)(K * 2) + (uint32_t)schunk;
        }
    }
    Bbase += (size_t)kp * KT * 128;

    char* ldsp = &lds[0];
    char* dA0 = ldsp + w * 4096;             // wave-uniform LDS dests
    char* dB0 = dA0 + 32768;

    // --- fragment read offsets (swizzled) -----------------------------------
    const int wm = w >> 2, wn = w & 3;
    const int fr = lane & 15, fq = lane >> 4;
    const int fr7 = fr & 7;
    const uint32_t co0 = (uint32_t)(((0 + fq) ^ fr7) << 4);   // k-step 0
    const uint32_t co1 = (uint32_t)(((4 + fq) ^ fr7) << 4);   // k-step 1
    uint32_t aRow[8], bRow[4];
#pragma unroll
    for (int m = 0; m < 8; ++m)
        aRow[m] = (uint32_t)(wm * 128 + m * 16 + fr) * 128;
#pragma unroll
    for (int n = 0; n < 4; ++n) {
        const int r = DUAL ? ((n < 2) ? (wn * 32 + n * 16 + fr)
                                      : (128 + wn * 32 + (n - 2) * 16 + fr))
                           : (wn * 64 + n * 16 + fr);
        bRow[n] = (uint32_t)r * 128 + 32768;
    }

    f32x4 acc[8][4] = {};

    // --- prologue: stage tile 0 into buf0 -----------------------------------
#pragma unroll
    for (int i = 0; i < 4; ++i) gload16(Abase + aOff[i], dA0 + i * 1024);
#pragma unroll
    for (int i = 0; i < 4; ++i) gload16(Bbase + bOff[i], dB0 + i * 1024);

    for (int kt = 0; kt < KT; ++kt) {
        const int buf = kt & 1;
        if (kt + 1 < KT) {                   // stage next tile, keep in flight
            const char* a = Abase + (size_t)(kt + 1) * 128;
            const char* b = Bbase + (size_t)(kt + 1) * 128;
            char* dA = dA0 + (buf ^ 1) * 65536;
            char* dB = dB0 + (buf ^ 1) * 65536;
#pragma unroll
            for (int i = 0; i < 4; ++i) gload16(a + aOff[i], dA + i * 1024);
#pragma unroll
            for (int i = 0; i < 4; ++i) gload16(b + bOff[i], dB + i * 1024);
            VMCNT8();                        // wait current tile only
        } else {
            VMCNT0();
        }
        RAWBAR();                            // tile kt resident for all waves

        const char* LA = ldsp + buf * 65536;
        bf16x8 af[4], bf[4];

        // phase 0: ks=0, m 0-3 (+ read B for ks=0)
#pragma unroll
        for (int n = 0; n < 4; ++n) bf[n] = *(const bf16x8*)(LA + bRow[n] + co0);
#pragma unroll
        for (int m = 0; m < 4; ++m) af[m] = *(const bf16x8*)(LA + aRow[m] + co0);
        RAWBAR(); __builtin_amdgcn_sched_barrier(0);
        __builtin_amdgcn_s_setprio(1);
#pragma unroll
        for (int m = 0; m < 4; ++m)
#pragma unroll
            for (int n = 0; n < 4; ++n)
                acc[m][n] = mfma16(af[m], bf[n], acc[m][n]);
        __builtin_amdgcn_s_setprio(0);

        // phase 1: ks=0, m 4-7
#pragma unroll
        for (int m = 0; m < 4; ++m) af[m] = *(const bf16x8*)(LA + aRow[4 + m] + co0);
        RAWBAR(); __builtin_amdgcn_sched_barrier(0);
        __builtin_amdgcn_s_setprio(1);
#pragma unroll
        for (int m = 0; m < 4; ++m)
#pragma unroll
            for (int n = 0; n < 4; ++n)
                acc[4 + m][n] = mfma16(af[m], bf[n], acc[4 + m][n]);
        __builtin_amdgcn_s_setprio(0);

        // phase 2: ks=1, m 0-3 (+ read B for ks=1)
#pragma unroll
        for (int n = 0; n < 4; ++n) bf[n] = *(const bf16x8*)(LA + bRow[n] + co1);
#pragma unroll
        for (int m = 0; m < 4; ++m) af[m] = *(const bf16x8*)(LA + aRow[m] + co1);
        RAWBAR(); __builtin_amdgcn_sched_barrier(0);
        __builtin_amdgcn_s_setprio(1);
#pragma unroll
        for (int m = 0; m < 4; ++m)
#pragma unroll
            for (int n = 0; n < 4; ++n)
                acc[m][n] = mfma16(af[m], bf[n], acc[m][n]);
        __builtin_amdgcn_s_setprio(0);

        // phase 3: ks=1, m 4-7
#pragma unroll
        for (int m = 0; m < 4; ++m) af[m] = *(const bf16x8*)(LA + aRow[4 + m] + co1);
        RAWBAR(); __builtin_amdgcn_sched_barrier(0);
        __builtin_amdgcn_s_setprio(1);
#pragma unroll
        for (int m = 0; m < 4; ++m)
#pragma unroll
            for (int n = 0; n < 4; ++n)
                acc[4 + m][n] = mfma16(af[m], bf[n], acc[4 + m][n]);
        __builtin_amdgcn_s_setprio(0);

        RAWBAR();                            // all reads done before next stage
    }

    // --- epilogue. C/D: col = lane&15 (fr), row = fq*4 + j (m89) ------------
    const int rb0 = m0 + wm * 128;
    const int rend = base + cnt;             // first row NOT owned by expert e
#pragma unroll
    for (int m = 0; m < 8; ++m) {
#pragma unroll
        for (int j = 0; j < 4; ++j) {
            const int grow = rb0 + m * 16 + fq * 4 + j;
            if (GROUPED && grow >= rend) continue;   // tail overlaps expert e+1
            if constexpr (DUAL) {
#pragma unroll
                for (int n = 0; n < 2; ++n) {
                    const int gcol = nt * 128 + wn * 32 + n * 16 + fr;
                    const float h1 = acc[m][n][j];
                    const float h2 = acc[m][n + 2][j];
                    OUTh[(size_t)grow * ldo + gcol] =
                        (bf16)(h1 / (1.f + expf(-h1)) * h2);
                }
            } else {
                float* O = OUTf + (size_t)kp * strideOut;
#pragma unroll
                for (int n = 0; n < 4; ++n) {
                    const int gcol = nt * 256 + wn * 64 + n * 16 + fr;
                    O[(size_t)grow * ldo + gcol] = acc[m][n][j];
                }
            }
        }
    }
}

// ---------------------------------------------------------------------------
// y[n] = sig[n]*(SP0+SP1+SP2+SP3)[n] + p0*EP[pos0] + p1*EP[pos1]
// ---------------------------------------------------------------------------
__global__ void combine_kernel(const float* __restrict__ SP,
                               const float* __restrict__ EP,
                               const int* __restrict__ pos_of,
                               const float* __restrict__ slotp,
                               const float* __restrict__ sig,
                               float* __restrict__ y)
{
    const int n  = blockIdx.x;
    const int p0 = pos_of[2 * n], p1 = pos_of[2 * n + 1];
    const float w0 = slotp[2 * n], w1 = slotp[2 * n + 1], sg = sig[n];
    const size_t PS = (size_t)N_TOK * C_DIM / 4;
    const f32x4* s  = (const f32x4*)SP + (size_t)n * (C_DIM / 4);
    const f32x4* e0 = (const f32x4*)(EP + (size_t)p0 * C_DIM);
    const f32x4* e1 = (const f32x4*)(EP + (size_t)p1 * C_DIM);
    f32x4*       o  = (f32x4*)(y + (size_t)n * C_DIM);
    for (int i = threadIdx.x; i < C_DIM / 4; i += 256) {
        f32x4 ssum = s[i] + s[i + PS] + s[i + 2 * PS] + s[i + 3 * PS];
        o[i] = sg * ssum + w0 * e0[i] + w1 * e1[i];
    }
}

// ---------------------------------------------------------------------------
extern "C" void kernel_launch(void* const* d_in, const int* in_sizes, int n_in,
                              void* d_out, int out_size, void* d_ws, size_t ws_size,
                              hipStream_t stream)
{
    const float* x     = (const float*)d_in[0];
    const float* gatew = (const float*)d_in[1];
    const float* efc1  = (const float*)d_in[2];
    const float* efc2  = (const float*)d_in[3];
    const float* eproj = (const float*)d_in[4];
    const float* sfc1  = (const float*)d_in[5];
    const float* sfc2  = (const float*)d_in[6];
    const float* sproj = (const float*)d_in[7];
    const float* sgate = (const float*)d_in[8];
    float* y = (float*)d_out;

    char* w = (char*)d_ws;
    size_t off = 0;
    auto take = [&](size_t bytes) {
        char* p = w + off;
        off = (off + bytes + 255) & ~(size_t)255;
        return p;
    };
    int*   counts    = (int*)  take(E_NUM * 4);
    int*   bases     = (int*)  take(E_NUM * 4);
    int*   slotexp   = (int*)  take(SLOTS * 4);
    float* slotp     = (float*)take(SLOTS * 4);
    int*   pos_of    = (int*)  take(SLOTS * 4);
    int*   row_token = (int*)  take(PADROWS * 4);
    float* sig       = (float*)take(N_TOK * 4);
    bf16*  Xs        = (bf16*) take((size_t)N_TOK   * C_DIM * 2);
    bf16*  Xg        = (bf16*) take((size_t)PADROWS * C_DIM * 2);
    bf16*  Hs        = (bf16*) take((size_t)N_TOK   * F_SH  * 2);
    bf16*  Hm        = (bf16*) take((size_t)PADROWS * F_MOE * 2);
    float* SP        = (float*)take((size_t)4 * N_TOK * C_DIM * 4);
    float* EP        = (float*)take((size_t)PADROWS * C_DIM * 4);
    bf16*  Wefc1     = (bf16*) take((size_t)E_NUM * F_MOE * C_DIM * 2);
    bf16*  Wefc2     = (bf16*) take((size_t)E_NUM * F_MOE * C_DIM * 2);
    bf16*  Weproj    = (bf16*) take((size_t)E_NUM * C_DIM * F_MOE * 2);
    bf16*  Wsfc1     = (bf16*) take((size_t)F_SH * C_DIM * 2);
    bf16*  Wsfc2     = (bf16*) take((size_t)F_SH * C_DIM * 2);
    bf16*  Wsproj    = (bf16*) take((size_t)C_DIM * F_SH * 2);
    (void)ws_size; (void)in_sizes; (void)n_in; (void)out_size;

    // f32 -> bf16 conversions
    cvt_kernel<<<(N_TOK * C_DIM) / 2048, 256, 0, stream>>>(x, Xs);
    cvt_kernel<<<(E_NUM * F_MOE * C_DIM) / 2048, 256, 0, stream>>>(efc1, Wefc1);
    cvt_kernel<<<(E_NUM * F_MOE * C_DIM) / 2048, 256, 0, stream>>>(efc2, Wefc2);
    cvt_kernel<<<(E_NUM * C_DIM * F_MOE) / 2048, 256, 0, stream>>>(eproj, Weproj);
    cvt_kernel<<<(F_SH * C_DIM) / 2048, 256, 0, stream>>>(sfc1, Wsfc1);
    cvt_kernel<<<(F_SH * C_DIM) / 2048, 256, 0, stream>>>(sfc2, Wsfc2);
    cvt_kernel<<<(C_DIM * F_SH) / 2048, 256, 0, stream>>>(sproj, Wsproj);

    router_kernel<<<N_TOK, 256, 0, stream>>>(x, gatew, sgate, slotexp, slotp, sig);
    scatter_kernel<<<1, 512, 0, stream>>>(slotexp, counts, bases, pos_of, row_token);
    gather_kernel<<<SLOTS, 256, 0, stream>>>(Xs, row_token, Xg);

    // shared fc: Hs = silu(Xs@sfc1^T)*(Xs@sfc2^T)         [2048 x 5632]
    gemm8<true, false, 1><<<dim3(F_SH / 128, N_TOK / 256, 1), 512, 0, stream>>>(
        Xs, C_DIM, Wsfc1, Wsfc2, 0, Hs, nullptr, F_SH, 0,
        nullptr, nullptr, C_DIM);

    // MoE fc (grouped): Hm = silu(Xg@fc1_e^T)*(Xg@fc2_e^T) [cnt_e x 1408]
    gemm8<true, true, 1><<<dim3(F_MOE / 128, SLOTS / 256, E_NUM), 512, 0, stream>>>(
        Xg, C_DIM, Wefc1, Wefc2, (size_t)F_MOE * C_DIM, Hm, nullptr, F_MOE, 0,
        bases, counts, C_DIM);

    // shared proj, 4-way K-split partials: SP[p] = Hs @ sproj^T (raw)
    gemm8<false, false, 4><<<dim3(C_DIM / 256, N_TOK / 256, 4), 512, 0, stream>>>(
        Hs, F_SH, Wsproj, nullptr, 0, nullptr, SP, C_DIM, (size_t)N_TOK * C_DIM,
        nullptr, nullptr, F_SH);

    // MoE proj (grouped): EP = Hm @ proj_e^T (raw)          [cnt_e x 2048]
    gemm8<false, true, 1><<<dim3(C_DIM / 256, SLOTS / 256, E_NUM), 512, 0, stream>>>(
        Hm, F_MOE, Weproj, nullptr, (size_t)C_DIM * F_MOE, nullptr, EP, C_DIM, 0,
        bases, counts, F_MOE);

    combine_kernel<<<N_TOK, 256, 0, stream>>>(SP, EP, pos_of, slotp, sig, y);
}

// Round 5
// 520.771 us; speedup vs baseline: 1.4722x; 1.0037x over previous
//
#include <hip/hip_runtime.h>
#include <hip/hip_bf16.h>
#include <math.h>
#include <stdint.h>

// Problem constants (B=2, T=1024 -> N=2048 tokens)
#define N_TOK   2048
#define C_DIM   2048
#define E_NUM   8
#define F_MOE   1408
#define F_SH    5632
#define SLOTS   4096            // N_TOK * TOPK
#define PADROWS 4608            // SLOTS + 512 slack for 256-row tile tails

typedef __bf16 bf16;
typedef __bf16 bf16x8 __attribute__((ext_vector_type(8)));
typedef float  f32x4  __attribute__((ext_vector_type(4)));

__device__ __forceinline__ f32x4 mfma16(bf16x8 a, bf16x8 b, f32x4 c) {
    return __builtin_amdgcn_mfma_f32_16x16x32_bf16(a, b, c, 0, 0, 0);
}
__device__ __forceinline__ void gload16(const void* g, void* l) {
    __builtin_amdgcn_global_load_lds(
        (const __attribute__((address_space(1))) void*)g,
        (__attribute__((address_space(3))) void*)l, 16, 0, 0);
}
#define RAWBAR() asm volatile("s_barrier" ::: "memory")
#define VMCNT8() asm volatile("s_waitcnt vmcnt(8)" ::: "memory")
#define VMCNT4() asm volatile("s_waitcnt vmcnt(4)" ::: "memory")
#define VMCNT0() asm volatile("s_waitcnt vmcnt(0)" ::: "memory")

// ---------------------------------------------------------------------------
// Router (unchanged, verified)
// ---------------------------------------------------------------------------
__global__ void router_kernel(const float* __restrict__ x,
                              const float* __restrict__ gate_w,
                              const float* __restrict__ sgate_w,
                              int* __restrict__ slotexp,
                              float* __restrict__ slotp,
                              float* __restrict__ sig)
{
    const int n   = blockIdx.x;
    const int tid = threadIdx.x;            // 256 threads
    const float* xr = x + (size_t)n * C_DIM;
    const int c0 = tid * 8;

    float xv[8];
#pragma unroll
    for (int j = 0; j < 8; ++j) xv[j] = xr[c0 + j];

    float dots[9];
#pragma unroll
    for (int e = 0; e < 9; ++e) {
        const float* wr = (e < 8) ? (gate_w + (size_t)e * C_DIM) : sgate_w;
        float p = 0.f;
#pragma unroll
        for (int j = 0; j < 8; ++j) p += xv[j] * wr[c0 + j];
#pragma unroll
        for (int off = 32; off > 0; off >>= 1) p += __shfl_down(p, off);
        dots[e] = p;
    }

    __shared__ float red[4][9];
    const int wid = tid >> 6, lane = tid & 63;
    if (lane == 0) {
#pragma unroll
        for (int e = 0; e < 9; ++e) red[wid][e] = dots[e];
    }
    __syncthreads();
    if (tid == 0) {
        float l[9];
#pragma unroll
        for (int e = 0; e < 9; ++e)
            l[e] = red[0][e] + red[1][e] + red[2][e] + red[3][e];
        float mx = l[0];
#pragma unroll
        for (int e = 1; e < 8; ++e) mx = fmaxf(mx, l[e]);
        float p[8], s = 0.f;
#pragma unroll
        for (int e = 0; e < 8; ++e) { p[e] = expf(l[e] - mx); s += p[e]; }
        const float inv = 1.f / s;
#pragma unroll
        for (int e = 0; e < 8; ++e) p[e] *= inv;
        int i1 = 0;
#pragma unroll
        for (int e = 1; e < 8; ++e) if (p[e] > p[i1]) i1 = e;
        int i2 = (i1 == 0) ? 1 : 0;
#pragma unroll
        for (int e = 0; e < 8; ++e) if (e != i1 && p[e] > p[i2]) i2 = e;
        slotexp[2 * n]     = i1;  slotp[2 * n]     = p[i1];
        slotexp[2 * n + 1] = i2;  slotp[2 * n + 1] = p[i2];
        sig[n] = 1.f / (1.f + expf(-l[8]));
    }
}

// ---------------------------------------------------------------------------
// Stable scatter (unchanged, verified)
// ---------------------------------------------------------------------------
__global__ void scatter_kernel(const int* __restrict__ slotexp,
                               int* __restrict__ counts, int* __restrict__ bases,
                               int* __restrict__ pos_of, int* __restrict__ row_token)
{
    const int tid = threadIdx.x;            // 512 threads = 8 waves
    const int w = tid >> 6, lane = tid & 63;
    __shared__ int cnt[E_NUM], base[E_NUM];

    int run = 0;
    for (int s0 = 0; s0 < SLOTS; s0 += 64) {
        int e = slotexp[s0 + lane];
        unsigned long long m = __ballot(e == w);
        run += __popcll(m);
    }
    if (lane == 0) cnt[w] = run;
    __syncthreads();
    if (tid == 0) {
        int b = 0;
        for (int e = 0; e < E_NUM; ++e) { base[e] = b; b += cnt[e]; }
    }
    __syncthreads();
    run = 0;
    for (int s0 = 0; s0 < SLOTS; s0 += 64) {
        const int s = s0 + lane;
        const int e = slotexp[s];
        unsigned long long m = __ballot(e == w);
        if (e == w) {
            const unsigned long long lt = (lane == 0) ? 0ull : (~0ull >> (64 - lane));
            const int pos = base[w] + run + __popcll(m & lt);
            pos_of[s]      = pos;
            row_token[pos] = s >> 1;
        }
        run += __popcll(m);
    }
    if (lane == 0) { counts[w] = cnt[w]; bases[w] = base[w]; }
}

// ---------------------------------------------------------------------------
// f32 -> bf16 elementwise, 8 elems/thread (size multiple of 2048)
// ---------------------------------------------------------------------------
__global__ void cvt_kernel(const float* __restrict__ in, bf16* __restrict__ out)
{
    const size_t i = ((size_t)blockIdx.x * 256 + threadIdx.x) * 8;
    f32x4 a = *(const f32x4*)(in + i);
    f32x4 b = *(const f32x4*)(in + i + 4);
    bf16x8 o;
#pragma unroll
    for (int j = 0; j < 4; ++j) { o[j] = (bf16)a[j]; o[4 + j] = (bf16)b[j]; }
    *(bf16x8*)(out + i) = o;
}

// ---------------------------------------------------------------------------
// Gather token rows into per-expert-contiguous Xg.
// ---------------------------------------------------------------------------
__global__ void gather_kernel(const bf16* __restrict__ Xs,
                              const int* __restrict__ row_token,
                              bf16* __restrict__ Xg)
{
    const int pos = blockIdx.x;
    const int t   = row_token[pos];
    const bf16x8* s = (const bf16x8*)(Xs + (size_t)t * C_DIM);
    bf16x8*       d = (bf16x8*)(Xg + (size_t)pos * C_DIM);
    d[threadIdx.x] = s[threadIdx.x];
}

// ---------------------------------------------------------------------------
// Deep-pipelined NT GEMM (T2+T3+T4+T5, m201-faithful 1.5-tile depth).
// out[m,n] = sum_k A[m,k]*B[n,k].  BM=256, BK=64 per tile split into two
// K=32 halves; 4 half-buffers x 32 KiB cycle mod 4 (A 16K + B 16K each).
// Half h is consumed in 2 phases; its buffer ((h)&3) is reused by half h+4,
// staged while computing h+1 -> 3 halves (12 loads/wave) in flight,
// steady-state s_waitcnt vmcnt(8), never drained until the last 2 halves.
// LDS layout: 128-B rows pair tile rows (2r',2r'+1); 16-B chunk index XOR
// (r'&7) on BOTH the gload source (pre-swizzle) and ds_read side -> every
// bank exactly 2-way (free). gload dest stays linear (wave base + lane*16).
// DUAL:  B-tile = fc1 panel rows 0-127 + fc2 rows 128-255; out=silu(h1)*h2.
// !DUAL: BN=256, raw f32 out. GROUPED: blockIdx.z=expert, epilogue masks
// rows >= base+cnt. KSPLIT>1: blockIdx.z = K-part partials.
// ---------------------------------------------------------------------------
template<bool DUAL, bool GROUPED, int KSPLIT>
__global__ __launch_bounds__(512, 1)
void gemm8(const bf16* __restrict__ A, int lda,
           const bf16* __restrict__ B1g, const bf16* __restrict__ B2g,
           size_t strideB,
           bf16* __restrict__ OUTh, float* __restrict__ OUTf, int ldo,
           size_t strideOut,
           const int* __restrict__ bases, const int* __restrict__ counts,
           int K)
{
    __shared__ char lds[131072];

    const int e    = GROUPED ? blockIdx.z : 0;
    const int base = GROUPED ? bases[e] : 0;
    const int cnt  = GROUPED ? counts[e] : 0x7fffffff;
    if (GROUPED && (int)blockIdx.y * 256 >= cnt) return;
    const int kp = (KSPLIT > 1) ? (int)blockIdx.z : 0;
    const int KT = (K / 64) / KSPLIT;
    const int H  = 2 * KT;                   // K=32 halves

    const int m0 = base + blockIdx.y * 256;
    const int nt = blockIdx.x;
    const int tid = threadIdx.x;
    const int w = tid >> 6, lane = tid & 63;

    // --- staging decode: dest is linear (wave base + lane*16); the content
    // chunk at slot (lane&7) of LDS row r' is (lane&7)^(r'&7), r'&7 == lane>>3
    const int l3  = lane >> 3;
    const int chS = (lane & 7) ^ l3;
    const int hiS = chS >> 2, ccS = chS & 3;
    const int rl  = w * 16 + 2 * l3 + hiS;   // tile row within 128-row group
    const size_t lda2 = (size_t)lda * 2, K2 = (size_t)K * 2;
    const size_t kpoff = (size_t)kp * KT * 128;

    const char* aSrc0 = (const char*)A + (size_t)(m0 + rl)       * lda2 + ccS * 16 + kpoff;
    const char* aSrc1 = (const char*)A + (size_t)(m0 + 128 + rl) * lda2 + ccS * 16 + kpoff;
    const bf16* B1 = B1g + (GROUPED ? (size_t)e * strideB : 0);
    const char* bSrc0;
    const char* bSrc1;
    if constexpr (DUAL) {
        const bf16* B2 = B2g + (GROUPED ? (size_t)e * strideB : 0);
        bSrc0 = (const char*)B1 + (size_t)(nt * 128 + rl) * K2 + ccS * 16 + kpoff;
        bSrc1 = (const char*)B2 + (size_t)(nt * 128 + rl) * K2 + ccS * 16 + kpoff;
    } else {
        bSrc0 = (const char*)B1 + (size_t)(nt * 256 + rl)       * K2 + ccS * 16 + kpoff;
        bSrc1 = (const char*)B1 + (size_t)(nt * 256 + 128 + rl) * K2 + ccS * 16 + kpoff;
    }
    char* ldsw = &lds[0] + w * 1024;         // wave-uniform LDS dest base

    auto issue = [&](int h) {                // 4 loads/wave per half
        const size_t ko = (size_t)(h >> 1) * 128 + (size_t)(h & 1) * 64;
        char* d = ldsw + (h & 3) * 32768;
        gload16(aSrc0 + ko, d);
        gload16(aSrc1 + ko, d + 8192);
        gload16(bSrc0 + ko, d + 16384);
        gload16(bSrc1 + ko, d + 24576);
    };

    // --- fragment read offsets (swizzled, constant across halves) ----------
    const int wm = w >> 2, wn = w & 3;
    const int fr = lane & 15, fq = lane >> 4;
    const int chRd = (((fr & 1) << 2) | fq) ^ ((fr >> 1) & 7);
    uint32_t aOff[8], bOff[4];
#pragma unroll
    for (int m = 0; m < 8; ++m)
        aOff[m] = (uint32_t)((wm * 64 + m * 8 + (fr >> 1)) * 128 + chRd * 16);
#pragma unroll
    for (int n = 0; n < 4; ++n) {
        int rp;
        if constexpr (DUAL)
            rp = (n < 2) ? (wn * 16 + n * 8) : (64 + wn * 16 + (n - 2) * 8);
        else
            rp = wn * 32 + n * 8;
        rp += (fr >> 1);
        bOff[n] = (uint32_t)(16384 + rp * 128 + chRd * 16);
    }

    f32x4 acc[8][4] = {};

    auto compute_half = [&](int h) {
        const char* LB = &lds[0] + (h & 3) * 32768;
        bf16x8 af[4], bf[4];
#pragma unroll
        for (int n = 0; n < 4; ++n) bf[n] = *(const bf16x8*)(LB + bOff[n]);
#pragma unroll
        for (int m = 0; m < 4; ++m) af[m] = *(const bf16x8*)(LB + aOff[m]);
        RAWBAR(); __builtin_amdgcn_sched_barrier(0);
        __builtin_amdgcn_s_setprio(1);
#pragma unroll
        for (int m = 0; m < 4; ++m)
#pragma unroll
            for (int n = 0; n < 4; ++n)
                acc[m][n] = mfma16(af[m], bf[n], acc[m][n]);
        __builtin_amdgcn_s_setprio(0);
#pragma unroll
        for (int m = 0; m < 4; ++m) af[m] = *(const bf16x8*)(LB + aOff[4 + m]);
        RAWBAR(); __builtin_amdgcn_sched_barrier(0);
        __builtin_amdgcn_s_setprio(1);
#pragma unroll
        for (int m = 0; m < 4; ++m)
#pragma unroll
            for (int n = 0; n < 4; ++n)
                acc[4 + m][n] = mfma16(af[m], bf[n], acc[4 + m][n]);
        __builtin_amdgcn_s_setprio(0);
    };

    // --- prologue: 3 halves in flight ---------------------------------------
    issue(0); issue(1); issue(2);

    for (int h = 0; h < H - 3; ++h) {
        VMCNT8();                            // half h landed (2 halves beyond)
        RAWBAR();                            // all waves: h resident, h-1 reads done
        issue(h + 3);                        // reuses buffer (h-1)&3
        compute_half(h);
    }
    VMCNT8(); RAWBAR(); compute_half(H - 3);
    VMCNT4(); RAWBAR(); compute_half(H - 2);
    VMCNT0(); RAWBAR(); compute_half(H - 1);

    // --- epilogue. C/D: col = lane&15 (fr), row = fq*4 + j (m89) ------------
    const int rb0 = m0 + wm * 128;
    const int rend = base + cnt;             // first row NOT owned by expert e
#pragma unroll
    for (int m = 0; m < 8; ++m) {
#pragma unroll
        for (int j = 0; j < 4; ++j) {
            const int grow = rb0 + m * 16 + fq * 4 + j;
            if (GROUPED && grow >= rend) continue;   // tail overlaps expert e+1
            if constexpr (DUAL) {
#pragma unroll
                for (int n = 0; n < 2; ++n) {
                    const int gcol = nt * 128 + wn * 32 + n * 16 + fr;
                    const float h1 = acc[m][n][j];
                    const float h2 = acc[m][n + 2][j];
                    OUTh[(size_t)grow * ldo + gcol] =
                        (bf16)(h1 / (1.f + expf(-h1)) * h2);
                }
            } else {
                float* O = OUTf + (size_t)kp * strideOut;
#pragma unroll
                for (int n = 0; n < 4; ++n) {
                    const int gcol = nt * 256 + wn * 64 + n * 16 + fr;
                    O[(size_t)grow * ldo + gcol] = acc[m][n][j];
                }
            }
        }
    }
}

// ---------------------------------------------------------------------------
// y[n] = sig[n]*(SP0+SP1+SP2+SP3)[n] + p0*EP[pos0] + p1*EP[pos1]
// ---------------------------------------------------------------------------
__global__ void combine_kernel(const float* __restrict__ SP,
                               const float* __restrict__ EP,
                               const int* __restrict__ pos_of,
                               const float* __restrict__ slotp,
                               const float* __restrict__ sig,
                               float* __restrict__ y)
{
    const int n  = blockIdx.x;
    const int p0 = pos_of[2 * n], p1 = pos_of[2 * n + 1];
    const float w0 = slotp[2 * n], w1 = slotp[2 * n + 1], sg = sig[n];
    const size_t PS = (size_t)N_TOK * C_DIM / 4;
    const f32x4* s  = (const f32x4*)SP + (size_t)n * (C_DIM / 4);
    const f32x4* e0 = (const f32x4*)(EP + (size_t)p0 * C_DIM);
    const f32x4* e1 = (const f32x4*)(EP + (size_t)p1 * C_DIM);
    f32x4*       o  = (f32x4*)(y + (size_t)n * C_DIM);
    for (int i = threadIdx.x; i < C_DIM / 4; i += 256) {
        f32x4 ssum = s[i] + s[i + PS] + s[i + 2 * PS] + s[i + 3 * PS];
        o[i] = sg * ssum + w0 * e0[i] + w1 * e1[i];
    }
}

// ---------------------------------------------------------------------------
extern "C" void kernel_launch(void* const* d_in, const int* in_sizes, int n_in,
                              void* d_out, int out_size, void* d_ws, size_t ws_size,
                              hipStream_t stream)
{
    const float* x     = (const float*)d_in[0];
    const float* gatew = (const float*)d_in[1];
    const float* efc1  = (const float*)d_in[2];
    const float* efc2  = (const float*)d_in[3];
    const float* eproj = (const float*)d_in[4];
    const float* sfc1  = (const float*)d_in[5];
    const float* sfc2  = (const float*)d_in[6];
    const float* sproj = (const float*)d_in[7];
    const float* sgate = (const float*)d_in[8];
    float* y = (float*)d_out;

    char* w = (char*)d_ws;
    size_t off = 0;
    auto take = [&](size_t bytes) {
        char* p = w + off;
        off = (off + bytes + 255) & ~(size_t)255;
        return p;
    };
    int*   counts    = (int*)  take(E_NUM * 4);
    int*   bases     = (int*)  take(E_NUM * 4);
    int*   slotexp   = (int*)  take(SLOTS * 4);
    float* slotp     = (float*)take(SLOTS * 4);
    int*   pos_of    = (int*)  take(SLOTS * 4);
    int*   row_token = (int*)  take(PADROWS * 4);
    float* sig       = (float*)take(N_TOK * 4);
    bf16*  Xs        = (bf16*) take((size_t)N_TOK   * C_DIM * 2);
    bf16*  Xg        = (bf16*) take((size_t)PADROWS * C_DIM * 2);
    bf16*  Hs        = (bf16*) take((size_t)N_TOK   * F_SH  * 2);
    bf16*  Hm        = (bf16*) take((size_t)PADROWS * F_MOE * 2);
    float* SP        = (float*)take((size_t)4 * N_TOK * C_DIM * 4);
    float* EP        = (float*)take((size_t)PADROWS * C_DIM * 4);
    bf16*  Wefc1     = (bf16*) take((size_t)E_NUM * F_MOE * C_DIM * 2);
    bf16*  Wefc2     = (bf16*) take((size_t)E_NUM * F_MOE * C_DIM * 2);
    bf16*  Weproj    = (bf16*) take((size_t)E_NUM * C_DIM * F_MOE * 2);
    bf16*  Wsfc1     = (bf16*) take((size_t)F_SH * C_DIM * 2);
    bf16*  Wsfc2     = (bf16*) take((size_t)F_SH * C_DIM * 2);
    bf16*  Wsproj    = (bf16*) take((size_t)C_DIM * F_SH * 2);
    (void)ws_size; (void)in_sizes; (void)n_in; (void)out_size;

    // f32 -> bf16 conversions
    cvt_kernel<<<(N_TOK * C_DIM) / 2048, 256, 0, stream>>>(x, Xs);
    cvt_kernel<<<(E_NUM * F_MOE * C_DIM) / 2048, 256, 0, stream>>>(efc1, Wefc1);
    cvt_kernel<<<(E_NUM * F_MOE * C_DIM) / 2048, 256, 0, stream>>>(efc2, Wefc2);
    cvt_kernel<<<(E_NUM * C_DIM * F_MOE) / 2048, 256, 0, stream>>>(eproj, Weproj);
    cvt_kernel<<<(F_SH * C_DIM) / 2048, 256, 0, stream>>>(sfc1, Wsfc1);
    cvt_kernel<<<(F_SH * C_DIM) / 2048, 256, 0, stream>>>(sfc2, Wsfc2);
    cvt_kernel<<<(C_DIM * F_SH) / 2048, 256, 0, stream>>>(sproj, Wsproj);

    router_kernel<<<N_TOK, 256, 0, stream>>>(x, gatew, sgate, slotexp, slotp, sig);
    scatter_kernel<<<1, 512, 0, stream>>>(slotexp, counts, bases, pos_of, row_token);
    gather_kernel<<<SLOTS, 256, 0, stream>>>(Xs, row_token, Xg);

    // shared fc: Hs = silu(Xs@sfc1^T)*(Xs@sfc2^T)          [2048 x 5632]
    gemm8<true, false, 1><<<dim3(F_SH / 128, N_TOK / 256, 1), 512, 0, stream>>>(
        Xs, C_DIM, Wsfc1, Wsfc2, 0, Hs, nullptr, F_SH, 0,
        nullptr, nullptr, C_DIM);

    // MoE fc (grouped): Hm = silu(Xg@fc1_e^T)*(Xg@fc2_e^T)  [cnt_e x 1408]
    gemm8<true, true, 1><<<dim3(F_MOE / 128, SLOTS / 256, E_NUM), 512, 0, stream>>>(
        Xg, C_DIM, Wefc1, Wefc2, (size_t)F_MOE * C_DIM, Hm, nullptr, F_MOE, 0,
        bases, counts, C_DIM);

    // shared proj, 4-way K-split partials: SP[p] = Hs @ sproj^T (raw)
    gemm8<false, false, 4><<<dim3(C_DIM / 256, N_TOK / 256, 4), 512, 0, stream>>>(
        Hs, F_SH, Wsproj, nullptr, 0, nullptr, SP, C_DIM, (size_t)N_TOK * C_DIM,
        nullptr, nullptr, F_SH);

    // MoE proj (grouped): EP = Hm @ proj_e^T (raw)           [cnt_e x 2048]
    gemm8<false, true, 1><<<dim3(C_DIM / 256, SLOTS / 256, E_NUM), 512, 0, stream>>>(
        Hm, F_MOE, Weproj, nullptr, (size_t)C_DIM * F_MOE, nullptr, EP, C_DIM, 0,
        bases, counts, F_MOE);

    combine_kernel<<<N_TOK, 256, 0, stream>>>(SP, EP, pos_of, slotp, sig, y);
}

// Round 6
// 490.735 us; speedup vs baseline: 1.5623x; 1.0612x over previous
//
#include <hip/hip_runtime.h>
#include <hip/hip_bf16.h>
#include <math.h>
#include <stdint.h>

// Problem constants (B=2, T=1024 -> N=2048 tokens)
#define N_TOK   2048
#define C_DIM   2048
#define E_NUM   8
#define F_MOE   1408
#define F_SH    5632
#define SLOTS   4096            // N_TOK * TOPK
#define PADROWS 4608            // SLOTS + 512 slack for 256-row tile tails

typedef __bf16 bf16;
typedef __bf16 bf16x8 __attribute__((ext_vector_type(8)));
typedef float  f32x4  __attribute__((ext_vector_type(4)));

__device__ __forceinline__ f32x4 mfma16(bf16x8 a, bf16x8 b, f32x4 c) {
    return __builtin_amdgcn_mfma_f32_16x16x32_bf16(a, b, c, 0, 0, 0);
}
__device__ __forceinline__ void gload16(const void* g, void* l) {
    __builtin_amdgcn_global_load_lds(
        (const __attribute__((address_space(1))) void*)g,
        (__attribute__((address_space(3))) void*)l, 16, 0, 0);
}
#define RAWBAR() asm volatile("s_barrier" ::: "memory")
#define VMCNT8() asm volatile("s_waitcnt vmcnt(8)" ::: "memory")
#define VMCNT4() asm volatile("s_waitcnt vmcnt(4)" ::: "memory")
#define VMCNT0() asm volatile("s_waitcnt vmcnt(0)" ::: "memory")

// ---------------------------------------------------------------------------
// Router (unchanged, verified)
// ---------------------------------------------------------------------------
__global__ void router_kernel(const float* __restrict__ x,
                              const float* __restrict__ gate_w,
                              const float* __restrict__ sgate_w,
                              int* __restrict__ slotexp,
                              float* __restrict__ slotp,
                              float* __restrict__ sig)
{
    const int n   = blockIdx.x;
    const int tid = threadIdx.x;            // 256 threads
    const float* xr = x + (size_t)n * C_DIM;
    const int c0 = tid * 8;

    float xv[8];
#pragma unroll
    for (int j = 0; j < 8; ++j) xv[j] = xr[c0 + j];

    float dots[9];
#pragma unroll
    for (int e = 0; e < 9; ++e) {
        const float* wr = (e < 8) ? (gate_w + (size_t)e * C_DIM) : sgate_w;
        float p = 0.f;
#pragma unroll
        for (int j = 0; j < 8; ++j) p += xv[j] * wr[c0 + j];
#pragma unroll
        for (int off = 32; off > 0; off >>= 1) p += __shfl_down(p, off);
        dots[e] = p;
    }

    __shared__ float red[4][9];
    const int wid = tid >> 6, lane = tid & 63;
    if (lane == 0) {
#pragma unroll
        for (int e = 0; e < 9; ++e) red[wid][e] = dots[e];
    }
    __syncthreads();
    if (tid == 0) {
        float l[9];
#pragma unroll
        for (int e = 0; e < 9; ++e)
            l[e] = red[0][e] + red[1][e] + red[2][e] + red[3][e];
        float mx = l[0];
#pragma unroll
        for (int e = 1; e < 8; ++e) mx = fmaxf(mx, l[e]);
        float p[8], s = 0.f;
#pragma unroll
        for (int e = 0; e < 8; ++e) { p[e] = expf(l[e] - mx); s += p[e]; }
        const float inv = 1.f / s;
#pragma unroll
        for (int e = 0; e < 8; ++e) p[e] *= inv;
        int i1 = 0;
#pragma unroll
        for (int e = 1; e < 8; ++e) if (p[e] > p[i1]) i1 = e;
        int i2 = (i1 == 0) ? 1 : 0;
#pragma unroll
        for (int e = 0; e < 8; ++e) if (e != i1 && p[e] > p[i2]) i2 = e;
        slotexp[2 * n]     = i1;  slotp[2 * n]     = p[i1];
        slotexp[2 * n + 1] = i2;  slotp[2 * n + 1] = p[i2];
        sig[n] = 1.f / (1.f + expf(-l[8]));
    }
}

// ---------------------------------------------------------------------------
// Stable scatter (unchanged, verified)
// ---------------------------------------------------------------------------
__global__ void scatter_kernel(const int* __restrict__ slotexp,
                               int* __restrict__ counts, int* __restrict__ bases,
                               int* __restrict__ pos_of, int* __restrict__ row_token)
{
    const int tid = threadIdx.x;            // 512 threads = 8 waves
    const int w = tid >> 6, lane = tid & 63;
    __shared__ int cnt[E_NUM], base[E_NUM];

    int run = 0;
    for (int s0 = 0; s0 < SLOTS; s0 += 64) {
        int e = slotexp[s0 + lane];
        unsigned long long m = __ballot(e == w);
        run += __popcll(m);
    }
    if (lane == 0) cnt[w] = run;
    __syncthreads();
    if (tid == 0) {
        int b = 0;
        for (int e = 0; e < E_NUM; ++e) { base[e] = b; b += cnt[e]; }
    }
    __syncthreads();
    run = 0;
    for (int s0 = 0; s0 < SLOTS; s0 += 64) {
        const int s = s0 + lane;
        const int e = slotexp[s];
        unsigned long long m = __ballot(e == w);
        if (e == w) {
            const unsigned long long lt = (lane == 0) ? 0ull : (~0ull >> (64 - lane));
            const int pos = base[w] + run + __popcll(m & lt);
            pos_of[s]      = pos;
            row_token[pos] = s >> 1;
        }
        run += __popcll(m);
    }
    if (lane == 0) { counts[w] = cnt[w]; bases[w] = base[w]; }
}

// ---------------------------------------------------------------------------
// ONE f32->bf16 conversion launch for x + all 6 weight tensors.
// Each block converts 2048 elems; segment decoded from cumulative block
// offsets (all sizes are multiples of 2048).
// ---------------------------------------------------------------------------
struct CvtArgs {
    const float* in[7];
    bf16*        out[7];
    int          cum[8];     // cumulative block counts, cum[0]=0
};

__global__ void cvt_all_kernel(CvtArgs a)
{
    int b = blockIdx.x;
    int s = 0;
#pragma unroll
    for (int k = 1; k < 7; ++k) s += (b >= a.cum[k]);
    const size_t i = ((size_t)(b - a.cum[s]) * 256 + threadIdx.x) * 8;
    const float* in = a.in[s];
    bf16* out = a.out[s];
    f32x4 lo = *(const f32x4*)(in + i);
    f32x4 hi = *(const f32x4*)(in + i + 4);
    bf16x8 o;
#pragma unroll
    for (int j = 0; j < 4; ++j) { o[j] = (bf16)lo[j]; o[4 + j] = (bf16)hi[j]; }
    *(bf16x8*)(out + i) = o;
}

// ---------------------------------------------------------------------------
// Gather token rows into per-expert-contiguous Xg.
// ---------------------------------------------------------------------------
__global__ void gather_kernel(const bf16* __restrict__ Xs,
                              const int* __restrict__ row_token,
                              bf16* __restrict__ Xg)
{
    const int pos = blockIdx.x;
    const int t   = row_token[pos];
    const bf16x8* s = (const bf16x8*)(Xs + (size_t)t * C_DIM);
    bf16x8*       d = (bf16x8*)(Xg + (size_t)pos * C_DIM);
    d[threadIdx.x] = s[threadIdx.x];
}

// ---------------------------------------------------------------------------
// Deep-pipelined NT GEMM (T2+T3+T4+T5).  out[m,n] = sum_k A[m,k]*B[n,k].
// BM=256, BK=64 split into two K=32 halves; 4 half-buffers x 32 KiB mod 4;
// 3 halves (12 loads/wave) in flight, steady-state vmcnt(8).
// Grid decode: GROUPED -> (x=expert, y=ytile, z=nt)  [expert fastest so
//   active blocks interleave uniformly through dispatch order];
// !GROUPED -> (x=nt, y=ytile, z=kp for KSPLIT partials).
// DUAL:  B-tile = fc1 panel rows 0-127 + fc2 rows 128-255; out=silu(h1)*h2.
// !DUAL: BN=256, bf16 partial out (scales/sums applied in combine).
// GROUPED epilogue masks rows >= base+cnt (tile tail overlaps next expert).
// ---------------------------------------------------------------------------
template<bool DUAL, bool GROUPED, int KSPLIT>
__global__ __launch_bounds__(512, 1)
void gemm8(const bf16* __restrict__ A, int lda,
           const bf16* __restrict__ B1g, const bf16* __restrict__ B2g,
           size_t strideB,
           bf16* __restrict__ OUTh, bf16* __restrict__ OUTq, int ldo,
           size_t strideOut,
           const int* __restrict__ bases, const int* __restrict__ counts,
           int K)
{
    __shared__ char lds[131072];

    const int e    = GROUPED ? blockIdx.x : 0;
    const int base = GROUPED ? bases[e] : 0;
    const int cnt  = GROUPED ? counts[e] : 0x7fffffff;
    const int yt   = blockIdx.y;
    if (GROUPED && yt * 256 >= cnt) return;
    const int nt = GROUPED ? (int)blockIdx.z : (int)blockIdx.x;
    const int kp = (!GROUPED && KSPLIT > 1) ? (int)blockIdx.z : 0;
    const int KT = (K / 64) / KSPLIT;
    const int H  = 2 * KT;                   // K=32 halves

    const int m0 = base + yt * 256;
    const int tid = threadIdx.x;
    const int w = tid >> 6, lane = tid & 63;

    // --- staging decode: dest is linear (wave base + lane*16); the content
    // chunk at slot (lane&7) of LDS row r' is (lane&7)^(r'&7), r'&7 == lane>>3
    const int l3  = lane >> 3;
    const int chS = (lane & 7) ^ l3;
    const int hiS = chS >> 2, ccS = chS & 3;
    const int rl  = w * 16 + 2 * l3 + hiS;   // tile row within 128-row group
    const size_t lda2 = (size_t)lda * 2, K2 = (size_t)K * 2;
    const size_t kpoff = (size_t)kp * KT * 128;

    const char* aSrc0 = (const char*)A + (size_t)(m0 + rl)       * lda2 + ccS * 16 + kpoff;
    const char* aSrc1 = (const char*)A + (size_t)(m0 + 128 + rl) * lda2 + ccS * 16 + kpoff;
    const bf16* B1 = B1g + (GROUPED ? (size_t)e * strideB : 0);
    const char* bSrc0;
    const char* bSrc1;
    if constexpr (DUAL) {
        const bf16* B2 = B2g + (GROUPED ? (size_t)e * strideB : 0);
        bSrc0 = (const char*)B1 + (size_t)(nt * 128 + rl) * K2 + ccS * 16 + kpoff;
        bSrc1 = (const char*)B2 + (size_t)(nt * 128 + rl) * K2 + ccS * 16 + kpoff;
    } else {
        bSrc0 = (const char*)B1 + (size_t)(nt * 256 + rl)       * K2 + ccS * 16 + kpoff;
        bSrc1 = (const char*)B1 + (size_t)(nt * 256 + 128 + rl) * K2 + ccS * 16 + kpoff;
    }
    char* ldsw = &lds[0] + w * 1024;         // wave-uniform LDS dest base

    auto issue = [&](int h) {                // 4 loads/wave per half
        const size_t ko = (size_t)(h >> 1) * 128 + (size_t)(h & 1) * 64;
        char* d = ldsw + (h & 3) * 32768;
        gload16(aSrc0 + ko, d);
        gload16(aSrc1 + ko, d + 8192);
        gload16(bSrc0 + ko, d + 16384);
        gload16(bSrc1 + ko, d + 24576);
    };

    // --- fragment read offsets (swizzled, constant across halves) ----------
    const int wm = w >> 2, wn = w & 3;
    const int fr = lane & 15, fq = lane >> 4;
    const int chRd = (((fr & 1) << 2) | fq) ^ ((fr >> 1) & 7);
    uint32_t aOff[8], bOff[4];
#pragma unroll
    for (int m = 0; m < 8; ++m)
        aOff[m] = (uint32_t)((wm * 64 + m * 8 + (fr >> 1)) * 128 + chRd * 16);
#pragma unroll
    for (int n = 0; n < 4; ++n) {
        int rp;
        if constexpr (DUAL)
            rp = (n < 2) ? (wn * 16 + n * 8) : (64 + wn * 16 + (n - 2) * 8);
        else
            rp = wn * 32 + n * 8;
        rp += (fr >> 1);
        bOff[n] = (uint32_t)(16384 + rp * 128 + chRd * 16);
    }

    f32x4 acc[8][4] = {};

    auto compute_half = [&](int h) {
        const char* LB = &lds[0] + (h & 3) * 32768;
        bf16x8 af[4], bf[4];
#pragma unroll
        for (int n = 0; n < 4; ++n) bf[n] = *(const bf16x8*)(LB + bOff[n]);
#pragma unroll
        for (int m = 0; m < 4; ++m) af[m] = *(const bf16x8*)(LB + aOff[m]);
        RAWBAR(); __builtin_amdgcn_sched_barrier(0);
        __builtin_amdgcn_s_setprio(1);
#pragma unroll
        for (int m = 0; m < 4; ++m)
#pragma unroll
            for (int n = 0; n < 4; ++n)
                acc[m][n] = mfma16(af[m], bf[n], acc[m][n]);
        __builtin_amdgcn_s_setprio(0);
#pragma unroll
        for (int m = 0; m < 4; ++m) af[m] = *(const bf16x8*)(LB + aOff[4 + m]);
        RAWBAR(); __builtin_amdgcn_sched_barrier(0);
        __builtin_amdgcn_s_setprio(1);
#pragma unroll
        for (int m = 0; m < 4; ++m)
#pragma unroll
            for (int n = 0; n < 4; ++n)
                acc[4 + m][n] = mfma16(af[m], bf[n], acc[4 + m][n]);
        __builtin_amdgcn_s_setprio(0);
    };

    // --- prologue: 3 halves in flight ---------------------------------------
    issue(0); issue(1); issue(2);

    for (int h = 0; h < H - 3; ++h) {
        VMCNT8();                            // half h landed (2 halves beyond)
        RAWBAR();                            // all waves: h resident, h-1 reads done
        issue(h + 3);                        // reuses buffer (h-1)&3
        compute_half(h);
    }
    VMCNT8(); RAWBAR(); compute_half(H - 3);
    VMCNT4(); RAWBAR(); compute_half(H - 2);
    VMCNT0(); RAWBAR(); compute_half(H - 1);

    // --- epilogue. C/D: col = lane&15 (fr), row = fq*4 + j (m89) ------------
    const int rb0 = m0 + wm * 128;
    const int rend = base + cnt;             // first row NOT owned by expert e
#pragma unroll
    for (int m = 0; m < 8; ++m) {
#pragma unroll
        for (int j = 0; j < 4; ++j) {
            const int grow = rb0 + m * 16 + fq * 4 + j;
            if (GROUPED && grow >= rend) continue;   // tail overlaps expert e+1
            if constexpr (DUAL) {
#pragma unroll
                for (int n = 0; n < 2; ++n) {
                    const int gcol = nt * 128 + wn * 32 + n * 16 + fr;
                    const float h1 = acc[m][n][j];
                    const float h2 = acc[m][n + 2][j];
                    OUTh[(size_t)grow * ldo + gcol] =
                        (bf16)(h1 / (1.f + expf(-h1)) * h2);
                }
            } else {
                bf16* O = OUTq + (size_t)kp * strideOut;
#pragma unroll
                for (int n = 0; n < 4; ++n) {
                    const int gcol = nt * 256 + wn * 64 + n * 16 + fr;
                    O[(size_t)grow * ldo + gcol] = (bf16)acc[m][n][j];
                }
            }
        }
    }
}

// ---------------------------------------------------------------------------
// y[n] = sig[n]*(SP0+SP1+SP2+SP3)[n] + p0*EP[pos0] + p1*EP[pos1]
// SP/EP are bf16 partials. 256 threads x 8 elems = 2048 = C_DIM.
// ---------------------------------------------------------------------------
__global__ void combine_kernel(const bf16* __restrict__ SP,
                               const bf16* __restrict__ EP,
                               const int* __restrict__ pos_of,
                               const float* __restrict__ slotp,
                               const float* __restrict__ sig,
                               float* __restrict__ y)
{
    const int n  = blockIdx.x;
    const int p0 = pos_of[2 * n], p1 = pos_of[2 * n + 1];
    const float w0 = slotp[2 * n], w1 = slotp[2 * n + 1], sg = sig[n];
    const size_t PS = (size_t)N_TOK * C_DIM;
    const size_t cidx = (size_t)n * C_DIM + threadIdx.x * 8;

    bf16x8 s0 = *(const bf16x8*)(SP + cidx);
    bf16x8 s1 = *(const bf16x8*)(SP + cidx + PS);
    bf16x8 s2 = *(const bf16x8*)(SP + cidx + 2 * PS);
    bf16x8 s3 = *(const bf16x8*)(SP + cidx + 3 * PS);
    bf16x8 a0 = *(const bf16x8*)(EP + (size_t)p0 * C_DIM + threadIdx.x * 8);
    bf16x8 a1 = *(const bf16x8*)(EP + (size_t)p1 * C_DIM + threadIdx.x * 8);

    float out[8];
#pragma unroll
    for (int j = 0; j < 8; ++j) {
        const float ssum = (float)s0[j] + (float)s1[j] + (float)s2[j] + (float)s3[j];
        out[j] = sg * ssum + w0 * (float)a0[j] + w1 * (float)a1[j];
    }
    f32x4 o0, o1;
#pragma unroll
    for (int j = 0; j < 4; ++j) { o0[j] = out[j]; o1[j] = out[4 + j]; }
    *(f32x4*)(y + cidx)     = o0;
    *(f32x4*)(y + cidx + 4) = o1;
}

// ---------------------------------------------------------------------------
extern "C" void kernel_launch(void* const* d_in, const int* in_sizes, int n_in,
                              void* d_out, int out_size, void* d_ws, size_t ws_size,
                              hipStream_t stream)
{
    const float* x     = (const float*)d_in[0];
    const float* gatew = (const float*)d_in[1];
    const float* efc1  = (const float*)d_in[2];
    const float* efc2  = (const float*)d_in[3];
    const float* eproj = (const float*)d_in[4];
    const float* sfc1  = (const float*)d_in[5];
    const float* sfc2  = (const float*)d_in[6];
    const float* sproj = (const float*)d_in[7];
    const float* sgate = (const float*)d_in[8];
    float* y = (float*)d_out;

    char* w = (char*)d_ws;
    size_t off = 0;
    auto take = [&](size_t bytes) {
        char* p = w + off;
        off = (off + bytes + 255) & ~(size_t)255;
        return p;
    };
    int*   counts    = (int*)  take(E_NUM * 4);
    int*   bases     = (int*)  take(E_NUM * 4);
    int*   slotexp   = (int*)  take(SLOTS * 4);
    float* slotp     = (float*)take(SLOTS * 4);
    int*   pos_of    = (int*)  take(SLOTS * 4);
    int*   row_token = (int*)  take(PADROWS * 4);
    float* sig       = (float*)take(N_TOK * 4);
    bf16*  Xs        = (bf16*) take((size_t)N_TOK   * C_DIM * 2);
    bf16*  Xg        = (bf16*) take((size_t)PADROWS * C_DIM * 2);
    bf16*  Hs        = (bf16*) take((size_t)N_TOK   * F_SH  * 2);
    bf16*  Hm        = (bf16*) take((size_t)PADROWS * F_MOE * 2);
    bf16*  SP        = (bf16*) take((size_t)4 * N_TOK * C_DIM * 2);
    bf16*  EP        = (bf16*) take((size_t)PADROWS * C_DIM * 2);
    bf16*  Wefc1     = (bf16*) take((size_t)E_NUM * F_MOE * C_DIM * 2);
    bf16*  Wefc2     = (bf16*) take((size_t)E_NUM * F_MOE * C_DIM * 2);
    bf16*  Weproj    = (bf16*) take((size_t)E_NUM * C_DIM * F_MOE * 2);
    bf16*  Wsfc1     = (bf16*) take((size_t)F_SH * C_DIM * 2);
    bf16*  Wsfc2     = (bf16*) take((size_t)F_SH * C_DIM * 2);
    bf16*  Wsproj    = (bf16*) take((size_t)C_DIM * F_SH * 2);
    (void)ws_size; (void)in_sizes; (void)n_in; (void)out_size;

    // single merged f32->bf16 pass (x + 6 weight tensors)
    CvtArgs ca;
    const int nbx  = (N_TOK * C_DIM) / 2048;                 // 2048
    const int nbe  = (E_NUM * F_MOE * C_DIM) / 2048;         // 11264
    const int nbs  = (F_SH * C_DIM) / 2048;                  // 5632
    ca.in[0] = x;     ca.out[0] = Xs;
    ca.in[1] = efc1;  ca.out[1] = Wefc1;
    ca.in[2] = efc2;  ca.out[2] = Wefc2;
    ca.in[3] = eproj; ca.out[3] = Weproj;
    ca.in[4] = sfc1;  ca.out[4] = Wsfc1;
    ca.in[5] = sfc2;  ca.out[5] = Wsfc2;
    ca.in[6] = sproj; ca.out[6] = Wsproj;
    ca.cum[0] = 0;
    ca.cum[1] = nbx;
    ca.cum[2] = nbx + nbe;
    ca.cum[3] = nbx + 2 * nbe;
    ca.cum[4] = nbx + 3 * nbe;
    ca.cum[5] = nbx + 3 * nbe + nbs;
    ca.cum[6] = nbx + 3 * nbe + 2 * nbs;
    ca.cum[7] = nbx + 3 * nbe + 3 * nbs;
    cvt_all_kernel<<<ca.cum[7], 256, 0, stream>>>(ca);

    router_kernel<<<N_TOK, 256, 0, stream>>>(x, gatew, sgate, slotexp, slotp, sig);
    scatter_kernel<<<1, 512, 0, stream>>>(slotexp, counts, bases, pos_of, row_token);
    gather_kernel<<<SLOTS, 256, 0, stream>>>(Xs, row_token, Xg);

    // shared fc: Hs = silu(Xs@sfc1^T)*(Xs@sfc2^T)          [2048 x 5632]
    gemm8<true, false, 1><<<dim3(F_SH / 128, N_TOK / 256, 1), 512, 0, stream>>>(
        Xs, C_DIM, Wsfc1, Wsfc2, 0, Hs, nullptr, F_SH, 0,
        nullptr, nullptr, C_DIM);

    // MoE fc (grouped, expert-fastest grid): Hm = silu(Xg@fc1_e^T)*(Xg@fc2_e^T)
    gemm8<true, true, 1><<<dim3(E_NUM, SLOTS / 256, F_MOE / 128), 512, 0, stream>>>(
        Xg, C_DIM, Wefc1, Wefc2, (size_t)F_MOE * C_DIM, Hm, nullptr, F_MOE, 0,
        bases, counts, C_DIM);

    // shared proj, 4-way K-split bf16 partials: SP[p] = Hs @ sproj^T
    gemm8<false, false, 4><<<dim3(C_DIM / 256, N_TOK / 256, 4), 512, 0, stream>>>(
        Hs, F_SH, Wsproj, nullptr, 0, nullptr, SP, C_DIM, (size_t)N_TOK * C_DIM,
        nullptr, nullptr, F_SH);

    // MoE proj (grouped, expert-fastest grid): EP = Hm @ proj_e^T (bf16)
    gemm8<false, true, 1><<<dim3(E_NUM, SLOTS / 256, C_DIM / 256), 512, 0, stream>>>(
        Hm, F_MOE, Weproj, nullptr, (size_t)C_DIM * F_MOE, nullptr, EP, C_DIM, 0,
        bases, counts, F_MOE);

    combine_kernel<<<N_TOK, 256, 0, stream>>>(SP, EP, pos_of, slotp, sig, y);
}